// Round 1
// baseline (86.689 us; speedup 1.0000x reference)
//
#include <hip/hip_runtime.h>
#include <math.h>

#define C_CH 256
#define PRE 14
#define NPOOL 7
#define PIX (NPOOL * NPOOL)            // 49
#define OUT_PER_ROI (C_CH * PIX)       // 12544
#define LDS_STRIDE 52                  // 49 padded: lane stride 4*52 floats -> 2-way bank alias (free)

// level offsets in floats inside HWC workspace
// p2: 256x256 -> 65536*256 ; p3: 128x128 ; p4: 64x64 ; p5: 32x32
#define OFF_P2 0
#define OFF_P3 16777216
#define OFF_P4 20971520
#define OFF_P5 22020096
#define WS_FLOATS 22282240

// ---------------- transpose CHW -> HWC (per level) ----------------
__global__ __launch_bounds__(256) void transpose_k(const float* __restrict__ src,
                                                   float* __restrict__ dst,
                                                   int HW /* H*W of this level */) {
    __shared__ float tile[64][65];
    const int hw0 = blockIdx.x * 64;
    const int c0  = blockIdx.y * 64;
    const int lane = threadIdx.x & 63;
    const int row  = threadIdx.x >> 6;
    #pragma unroll
    for (int cc = row; cc < 64; cc += 4)
        tile[cc][lane] = src[(size_t)(c0 + cc) * HW + hw0 + lane];
    __syncthreads();
    #pragma unroll
    for (int hh = row; hh < 64; hh += 4)
        dst[(size_t)(hw0 + hh) * C_CH + c0 + lane] = tile[lane][hh];
}

// ---------------- main ROI-align + 2x2 maxpool ----------------
template <bool HWC>
__global__ __launch_bounds__(256) void roi_align_k(
    const float* __restrict__ p2, const float* __restrict__ p3,
    const float* __restrict__ p4, const float* __restrict__ p5,
    const float* __restrict__ ws, const float* __restrict__ rois,
    float* __restrict__ out) {

    __shared__ float sxw0[PRE], sxw1[PRE], syw0[PRE], syw1[PRE];
    __shared__ int   sxc0[PRE], sxc1[PRE], syc0[PRE], syc1[PRE];
    __shared__ float sout[C_CH * LDS_STRIDE];   // 53248 B

    const int n = blockIdx.x;
    const float x1 = rois[n * 5 + 1];
    const float y1 = rois[n * 5 + 2];
    const float x2 = rois[n * 5 + 3];
    const float y2 = rois[n * 5 + 4];

    float w = x2 - x1; w = (w <= 0.f) ? 1e-14f : w;
    float h = y2 - y1; h = (h <= 0.f) ? 1e-14f : h;
    float kf = 4.f + log2f(sqrtf(w * h) * (1.f / 224.f));
    kf = fminf(fmaxf(kf, 2.f), 5.f);
    const float kr = rintf(kf);           // round-half-even, matches jnp.round
    const int   lvl = (int)kr - 2;        // 0..3
    const float scale = exp2f(kr);        // 4..32
    const int   HW = 256 >> lvl;

    const int t = threadIdx.x;

    // per-ROI separable interpolation tables (x: threads 0..13, y: threads 14..27)
    if (t < 2 * PRE) {
        const bool isx = t < PRE;
        const int  j = isx ? t : t - PRE;
        const float a1 = isx ? x1 : y1;
        const float a2 = isx ? x2 : y2;
        const float a1s = a1 / scale, a2s = a2 / scale;
        const float cen  = (a1s + a2s) * 0.5f;
        const float half = (a2s - a1s) * 0.5f;
        const float tt = -1.f + (2.f / 13.f) * (float)j;
        const float p  = cen + tt * half;
        const float p0 = floorf(p);
        const float d  = p - p0;
        const float HWf = (float)HW;
        const float m0 = (p0 >= 0.f && p0 < HWf) ? 1.f : 0.f;
        const float m1 = (p0 + 1.f >= 0.f && p0 + 1.f < HWf) ? 1.f : 0.f;
        const int c0i = min(max((int)p0, 0), HW - 1);
        const int c1i = min(max((int)p0 + 1, 0), HW - 1);
        if (isx) { sxw0[j] = (1.f - d) * m0; sxw1[j] = d * m1; sxc0[j] = c0i; sxc1[j] = c1i; }
        else     { syw0[j] = (1.f - d) * m0; syw1[j] = d * m1; syc0[j] = c0i; syc1[j] = c1i; }
    }
    __syncthreads();

    const int lane  = t & 63;
    const int q     = t >> 6;        // 0..3, pixel phase
    const int cbase = lane * 4;      // 4 channels per lane

    const float* __restrict__ fb;
    if (HWC) {
        const int off = (lvl == 0) ? OFF_P2 : (lvl == 1) ? OFF_P3 : (lvl == 2) ? OFF_P4 : OFF_P5;
        fb = ws + off + cbase;
    } else {
        fb = (lvl == 0) ? p2 : (lvl == 1) ? p3 : (lvl == 2) ? p4 : p5;
    }
    const int HW2 = HW * HW;

    for (int p = q; p < PIX; p += 4) {
        const int oy = p / 7;
        const int ox = p - oy * 7;
        float4 m = make_float4(-3.4e38f, -3.4e38f, -3.4e38f, -3.4e38f);
        #pragma unroll
        for (int sy = 0; sy < 2; ++sy) {
            const int i = oy * 2 + sy;
            const float wy0 = syw0[i], wy1 = syw1[i];
            const int   yc0 = syc0[i], yc1 = syc1[i];
            #pragma unroll
            for (int sx = 0; sx < 2; ++sx) {
                const int j = ox * 2 + sx;
                const float wx0 = sxw0[j], wx1 = sxw1[j];
                const int   xc0 = sxc0[j], xc1 = sxc1[j];
                float4 v;
                if (HWC) {
                    const float4 a00 = *(const float4*)(fb + ((size_t)(yc0 * HW + xc0) << 8));
                    const float4 a01 = *(const float4*)(fb + ((size_t)(yc0 * HW + xc1) << 8));
                    const float4 a10 = *(const float4*)(fb + ((size_t)(yc1 * HW + xc0) << 8));
                    const float4 a11 = *(const float4*)(fb + ((size_t)(yc1 * HW + xc1) << 8));
                    v.x = wy0 * (wx0 * a00.x + wx1 * a01.x) + wy1 * (wx0 * a10.x + wx1 * a11.x);
                    v.y = wy0 * (wx0 * a00.y + wx1 * a01.y) + wy1 * (wx0 * a10.y + wx1 * a11.y);
                    v.z = wy0 * (wx0 * a00.z + wx1 * a01.z) + wy1 * (wx0 * a10.z + wx1 * a11.z);
                    v.w = wy0 * (wx0 * a00.w + wx1 * a01.w) + wy1 * (wx0 * a10.w + wx1 * a11.w);
                } else {
                    float vv[4];
                    #pragma unroll
                    for (int k = 0; k < 4; ++k) {
                        const size_t cb = (size_t)(cbase + k) * HW2;
                        const float a00 = fb[cb + yc0 * HW + xc0];
                        const float a01 = fb[cb + yc0 * HW + xc1];
                        const float a10 = fb[cb + yc1 * HW + xc0];
                        const float a11 = fb[cb + yc1 * HW + xc1];
                        vv[k] = wy0 * (wx0 * a00 + wx1 * a01) + wy1 * (wx0 * a10 + wx1 * a11);
                    }
                    v.x = vv[0]; v.y = vv[1]; v.z = vv[2]; v.w = vv[3];
                }
                m.x = fmaxf(m.x, v.x);
                m.y = fmaxf(m.y, v.y);
                m.z = fmaxf(m.z, v.z);
                m.w = fmaxf(m.w, v.w);
            }
        }
        sout[(cbase + 0) * LDS_STRIDE + p] = m.x;
        sout[(cbase + 1) * LDS_STRIDE + p] = m.y;
        sout[(cbase + 2) * LDS_STRIDE + p] = m.z;
        sout[(cbase + 3) * LDS_STRIDE + p] = m.w;
    }
    __syncthreads();

    // coalesced NCHW write
    const size_t ob = (size_t)n * OUT_PER_ROI;
    for (int o = t; o < OUT_PER_ROI; o += 256) {
        const int c  = o / PIX;
        const int pp = o - c * PIX;
        out[ob + o] = sout[c * LDS_STRIDE + pp];
    }
}

extern "C" void kernel_launch(void* const* d_in, const int* in_sizes, int n_in,
                              void* d_out, int out_size, void* d_ws, size_t ws_size,
                              hipStream_t stream) {
    const float* p2   = (const float*)d_in[0];
    const float* p3   = (const float*)d_in[1];
    const float* p4   = (const float*)d_in[2];
    const float* p5   = (const float*)d_in[3];
    const float* rois = (const float*)d_in[4];
    float* out = (float*)d_out;
    const int N = in_sizes[4] / 5;

    const size_t need = (size_t)WS_FLOATS * sizeof(float);
    if (ws_size >= need) {
        float* ws = (float*)d_ws;
        transpose_k<<<dim3(65536 / 64, 4), 256, 0, stream>>>(p2, ws + OFF_P2, 65536);
        transpose_k<<<dim3(16384 / 64, 4), 256, 0, stream>>>(p3, ws + OFF_P3, 16384);
        transpose_k<<<dim3(4096 / 64, 4),  256, 0, stream>>>(p4, ws + OFF_P4, 4096);
        transpose_k<<<dim3(1024 / 64, 4),  256, 0, stream>>>(p5, ws + OFF_P5, 1024);
        roi_align_k<true><<<N, 256, 0, stream>>>(p2, p3, p4, p5, ws, rois, out);
    } else {
        roi_align_k<false><<<N, 256, 0, stream>>>(p2, p3, p4, p5, nullptr, rois, out);
    }
}

// Round 2
// 58.244 us; speedup vs baseline: 1.4884x; 1.4884x over previous
//
#include <hip/hip_runtime.h>
#include <math.h>

#define C_CH 256
#define PRE 14
#define NPOOL 7
#define PIX (NPOOL * NPOOL)            // 49
#define OUT_PER_ROI (C_CH * PIX)       // 12544
#define HALF_C 128
#define HALF_OUT (HALF_C * PIX)        // 6272
#define SROW 132                       // 128 + 4 pad (16B-aligned rows for b128 writes)

// level offsets in bf16 elements inside HWC workspace
#define OFF_P2 0
#define OFF_P3 16777216u
#define OFF_P4 20971520u
#define OFF_P5 22020096u
#define WS_ELEMS 22282240u

static __device__ __forceinline__ unsigned short f2bf(float f) {
    unsigned int u = __float_as_uint(f);
    unsigned int r = (u + 0x7FFFu + ((u >> 16) & 1u)) >> 16;   // RNE
    return (unsigned short)r;
}
static __device__ __forceinline__ float bf2f(unsigned short b) {
    return __uint_as_float(((unsigned int)b) << 16);
}

// ---------------- fused transpose CHW fp32 -> HWC bf16 (all 4 levels) ----------------
__global__ __launch_bounds__(256) void transpose_all_k(
    const float* __restrict__ p2, const float* __restrict__ p3,
    const float* __restrict__ p4, const float* __restrict__ p5,
    unsigned short* __restrict__ ws) {
    __shared__ float tile[64][65];
    int b = blockIdx.x;
    const float* __restrict__ src;
    int HW2; unsigned int off;
    if (b < 4096)      { src = p2; HW2 = 65536; off = OFF_P2; }
    else if (b < 5120) { src = p3; HW2 = 16384; off = OFF_P3; b -= 4096; }
    else if (b < 5376) { src = p4; HW2 = 4096;  off = OFF_P4; b -= 5120; }
    else               { src = p5; HW2 = 1024;  off = OFF_P5; b -= 5376; }
    const int c0  = (b & 3) << 6;
    const int hw0 = (b >> 2) << 6;
    const int lane = threadIdx.x & 63;
    const int row  = threadIdx.x >> 6;
    #pragma unroll
    for (int cc = row; cc < 64; cc += 4)
        tile[cc][lane] = src[(size_t)(c0 + cc) * HW2 + hw0 + lane];
    __syncthreads();
    #pragma unroll
    for (int hh = row; hh < 64; hh += 4)
        ws[off + (size_t)(hw0 + hh) * C_CH + c0 + lane] = f2bf(tile[lane][hh]);
}

// ---------------- main ROI-align + 2x2 maxpool (128 channels per block) ----------------
template <bool HWC>
__global__ __launch_bounds__(256, 6) void roi_align_k(
    const float* __restrict__ p2, const float* __restrict__ p3,
    const float* __restrict__ p4, const float* __restrict__ p5,
    const unsigned short* __restrict__ ws, const float* __restrict__ rois,
    float* __restrict__ out) {

    __shared__ float sxw0[PRE], sxw1[PRE], syw0[PRE], syw1[PRE];
    __shared__ int   sxc0[PRE], sxc1[PRE], syc0[PRE], syc1[PRE];
    __shared__ float sout[PIX * SROW];          // 49*132*4 = 25872 B

    const int n   = blockIdx.x;
    const int ch0 = blockIdx.y << 7;            // 0 or 128
    const float x1 = rois[n * 5 + 1];
    const float y1 = rois[n * 5 + 2];
    const float x2 = rois[n * 5 + 3];
    const float y2 = rois[n * 5 + 4];

    float w = x2 - x1; w = (w <= 0.f) ? 1e-14f : w;
    float h = y2 - y1; h = (h <= 0.f) ? 1e-14f : h;
    float kf = 4.f + log2f(sqrtf(w * h) * (1.f / 224.f));
    kf = fminf(fmaxf(kf, 2.f), 5.f);
    const float kr = rintf(kf);                 // round-half-even == jnp.round
    const int   lvl = (int)kr - 2;              // 0..3
    const float scale = exp2f(kr);
    const int   HW = 256 >> lvl;

    const int t = threadIdx.x;

    if (t < 2 * PRE) {
        const bool isx = t < PRE;
        const int  j = isx ? t : t - PRE;
        const float a1 = isx ? x1 : y1;
        const float a2 = isx ? x2 : y2;
        const float a1s = a1 / scale, a2s = a2 / scale;
        const float cen  = (a1s + a2s) * 0.5f;
        const float half = (a2s - a1s) * 0.5f;
        const float tt = -1.f + (2.f / 13.f) * (float)j;
        const float p  = cen + tt * half;
        const float p0 = floorf(p);
        const float d  = p - p0;
        const float HWf = (float)HW;
        const float m0 = (p0 >= 0.f && p0 < HWf) ? 1.f : 0.f;
        const float m1 = (p0 + 1.f >= 0.f && p0 + 1.f < HWf) ? 1.f : 0.f;
        const int c0i = min(max((int)p0, 0), HW - 1);
        const int c1i = min(max((int)p0 + 1, 0), HW - 1);
        if (isx) { sxw0[j] = (1.f - d) * m0; sxw1[j] = d * m1; sxc0[j] = c0i; sxc1[j] = c1i; }
        else     { syw0[j] = (1.f - d) * m0; syw1[j] = d * m1; syc0[j] = c0i; syc1[j] = c1i; }
    }
    __syncthreads();

    const int g     = t & 31;                   // channel group within half: 32 x 4ch = 128
    const int ph    = t >> 5;                   // 0..7 pixel phase
    const int cbase = ch0 + (g << 2);

    const unsigned short* __restrict__ fb = nullptr;
    const float* __restrict__ fbF = nullptr;
    if (HWC) {
        const unsigned int off = (lvl == 0) ? OFF_P2 : (lvl == 1) ? OFF_P3 : (lvl == 2) ? OFF_P4 : OFF_P5;
        fb = ws + off + cbase;
    } else {
        fbF = (lvl == 0) ? p2 : (lvl == 1) ? p3 : (lvl == 2) ? p4 : p5;
    }
    const int HW2 = HW * HW;

    for (int p = ph; p < PIX; p += 8) {
        const int oy = p / 7;
        const int ox = p - oy * 7;
        float4 m = make_float4(-3.4e38f, -3.4e38f, -3.4e38f, -3.4e38f);
        #pragma unroll
        for (int sy = 0; sy < 2; ++sy) {
            const int i = oy * 2 + sy;
            const float wy0 = syw0[i], wy1 = syw1[i];
            const int   yc0 = syc0[i], yc1 = syc1[i];
            #pragma unroll
            for (int sx = 0; sx < 2; ++sx) {
                const int j = ox * 2 + sx;
                const float wx0 = sxw0[j], wx1 = sxw1[j];
                const int   xc0 = sxc0[j], xc1 = sxc1[j];
                float4 v;
                if (HWC) {
                    const ushort4 a00 = *(const ushort4*)(fb + ((yc0 * HW + xc0) << 8));
                    const ushort4 a01 = *(const ushort4*)(fb + ((yc0 * HW + xc1) << 8));
                    const ushort4 a10 = *(const ushort4*)(fb + ((yc1 * HW + xc0) << 8));
                    const ushort4 a11 = *(const ushort4*)(fb + ((yc1 * HW + xc1) << 8));
                    v.x = wy0 * (wx0 * bf2f(a00.x) + wx1 * bf2f(a01.x)) + wy1 * (wx0 * bf2f(a10.x) + wx1 * bf2f(a11.x));
                    v.y = wy0 * (wx0 * bf2f(a00.y) + wx1 * bf2f(a01.y)) + wy1 * (wx0 * bf2f(a10.y) + wx1 * bf2f(a11.y));
                    v.z = wy0 * (wx0 * bf2f(a00.z) + wx1 * bf2f(a01.z)) + wy1 * (wx0 * bf2f(a10.z) + wx1 * bf2f(a11.z));
                    v.w = wy0 * (wx0 * bf2f(a00.w) + wx1 * bf2f(a01.w)) + wy1 * (wx0 * bf2f(a10.w) + wx1 * bf2f(a11.w));
                } else {
                    float vv[4];
                    #pragma unroll
                    for (int k = 0; k < 4; ++k) {
                        const size_t cb = (size_t)(cbase + k) * HW2;
                        const float a00 = fbF[cb + yc0 * HW + xc0];
                        const float a01 = fbF[cb + yc0 * HW + xc1];
                        const float a10 = fbF[cb + yc1 * HW + xc0];
                        const float a11 = fbF[cb + yc1 * HW + xc1];
                        vv[k] = wy0 * (wx0 * a00 + wx1 * a01) + wy1 * (wx0 * a10 + wx1 * a11);
                    }
                    v.x = vv[0]; v.y = vv[1]; v.z = vv[2]; v.w = vv[3];
                }
                m.x = fmaxf(m.x, v.x);
                m.y = fmaxf(m.y, v.y);
                m.z = fmaxf(m.z, v.z);
                m.w = fmaxf(m.w, v.w);
            }
        }
        // pixel-major, b128 conflict-free (wave-uniform p per half-wave, lanes contiguous)
        *(float4*)&sout[p * SROW + (g << 2)] = m;
    }
    __syncthreads();

    // coalesced NCHW write of this channel-half
    const size_t ob = (size_t)n * OUT_PER_ROI + (size_t)ch0 * PIX;
    for (int o = t; o < HALF_OUT; o += 256) {
        const int c  = o / PIX;
        const int pp = o - c * PIX;
        out[ob + o] = sout[pp * SROW + c];
    }
}

extern "C" void kernel_launch(void* const* d_in, const int* in_sizes, int n_in,
                              void* d_out, int out_size, void* d_ws, size_t ws_size,
                              hipStream_t stream) {
    const float* p2   = (const float*)d_in[0];
    const float* p3   = (const float*)d_in[1];
    const float* p4   = (const float*)d_in[2];
    const float* p5   = (const float*)d_in[3];
    const float* rois = (const float*)d_in[4];
    float* out = (float*)d_out;
    const int N = in_sizes[4] / 5;

    const size_t need = (size_t)WS_ELEMS * sizeof(unsigned short);
    if (ws_size >= need) {
        unsigned short* ws = (unsigned short*)d_ws;
        transpose_all_k<<<5440, 256, 0, stream>>>(p2, p3, p4, p5, ws);
        roi_align_k<true><<<dim3(N, 2), 256, 0, stream>>>(p2, p3, p4, p5, ws, rois, out);
    } else {
        roi_align_k<false><<<dim3(N, 2), 256, 0, stream>>>(p2, p3, p4, p5, nullptr, rois, out);
    }
}

// Round 3
// 56.477 us; speedup vs baseline: 1.5349x; 1.0313x over previous
//
#include <hip/hip_runtime.h>
#include <math.h>

#define C_CH 256
#define PRE 14
#define NPOOL 7
#define PIX (NPOOL * NPOOL)            // 49
#define OUT_PER_ROI (C_CH * PIX)       // 12544
#define HALF_C 128
#define HALF_OUT (HALF_C * PIX)        // 6272
#define SROW 132                       // sout: 128 + 4 pad

// level offsets in bf16 elements inside HWC workspace
#define OFF_P2 0
#define OFF_P3 16777216u
#define OFF_P4 20971520u
#define OFF_P5 22020096u
#define WS_ELEMS 22282240u

#define TROW 264                       // transpose LDS row stride in ushorts (528 B, 16B-aligned)

static __device__ __forceinline__ unsigned short f2bf(float f) {
    unsigned int u = __float_as_uint(f);
    unsigned int r = (u + 0x7FFFu + ((u >> 16) & 1u)) >> 16;   // RNE
    return (unsigned short)r;
}
static __device__ __forceinline__ float bf2f(unsigned short b) {
    return __uint_as_float(((unsigned int)b) << 16);
}

// ---------------- fused transpose CHW fp32 -> HWC bf16 (all 4 levels) ----------------
// Block tile: 64 hw positions x 256 channels. Phase 1: coalesced 256B scalar loads
// (lane = hw), b64 LDS writes. Phase 2: b128 LDS reads + fully-contiguous 16B/lane
// global stores (32 KB contiguous span per block).
__global__ __launch_bounds__(256) void transpose_all_k(
    const float* __restrict__ p2, const float* __restrict__ p3,
    const float* __restrict__ p4, const float* __restrict__ p5,
    unsigned short* __restrict__ ws) {
    __shared__ unsigned short lds[64 * TROW];   // 33792 B

    int b = blockIdx.x;
    const float* __restrict__ src;
    int HW2; unsigned int off;
    if (b < 1024)      { src = p2; HW2 = 65536; off = OFF_P2; }
    else if (b < 1280) { src = p3; HW2 = 16384; off = OFF_P3; b -= 1024; }
    else if (b < 1344) { src = p4; HW2 = 4096;  off = OFF_P4; b -= 1280; }
    else               { src = p5; HW2 = 1024;  off = OFF_P5; b -= 1344; }
    const int hw0 = b << 6;

    const int t   = threadIdx.x;
    const int hwl = t & 63;
    const int qb  = t >> 6;            // 0..3

    #pragma unroll
    for (int p = 0; p < 16; ++p) {
        const int c0 = (qb << 6) + (p << 2);   // channel quad base: 64*qb + 4*p
        const size_t base = (size_t)c0 * HW2 + hw0 + hwl;
        const float v0 = src[base];
        const float v1 = src[base + HW2];
        const float v2 = src[base + 2 * (size_t)HW2];
        const float v3 = src[base + 3 * (size_t)HW2];
        ushort4 w;
        w.x = f2bf(v0); w.y = f2bf(v1); w.z = f2bf(v2); w.w = f2bf(v3);
        *(ushort4*)&lds[hwl * TROW + c0] = w;
    }
    __syncthreads();

    // 32 KB contiguous output span: dst byte offset o in [0, 32768)
    unsigned short* __restrict__ dst = ws + off + ((size_t)hw0 << 8);
    #pragma unroll
    for (int p = 0; p < 8; ++p) {
        const int o  = (p << 12) + (t << 4);   // byte offset
        const int hw = o >> 9;
        const int cb = o & 511;
        const uint4 v = *(const uint4*)((const char*)lds + hw * 528 + cb);
        *(uint4*)((char*)dst + o) = v;
    }
}

// ---------------- main ROI-align + 2x2 maxpool (128 channels per block) ----------------
template <bool HWC>
__global__ __launch_bounds__(256, 6) void roi_align_k(
    const float* __restrict__ p2, const float* __restrict__ p3,
    const float* __restrict__ p4, const float* __restrict__ p5,
    const unsigned short* __restrict__ ws, const float* __restrict__ rois,
    float* __restrict__ out) {

    __shared__ float sxw0[PRE], sxw1[PRE], syw0[PRE], syw1[PRE];
    __shared__ int   sxc0[PRE], sxc1[PRE], syc0[PRE], syc1[PRE];
    __shared__ float sout[PIX * SROW];          // 25872 B

    const int n   = blockIdx.x;
    const int ch0 = blockIdx.y << 7;            // 0 or 128
    const float x1 = rois[n * 5 + 1];
    const float y1 = rois[n * 5 + 2];
    const float x2 = rois[n * 5 + 3];
    const float y2 = rois[n * 5 + 4];

    float w = x2 - x1; w = (w <= 0.f) ? 1e-14f : w;
    float h = y2 - y1; h = (h <= 0.f) ? 1e-14f : h;
    float kf = 4.f + log2f(sqrtf(w * h) * (1.f / 224.f));
    kf = fminf(fmaxf(kf, 2.f), 5.f);
    const float kr = rintf(kf);                 // round-half-even == jnp.round
    const int   lvl = (int)kr - 2;              // 0..3
    const float scale = exp2f(kr);
    const int   HW = 256 >> lvl;

    const int t = threadIdx.x;

    if (t < 2 * PRE) {
        const bool isx = t < PRE;
        const int  j = isx ? t : t - PRE;
        const float a1 = isx ? x1 : y1;
        const float a2 = isx ? x2 : y2;
        const float a1s = a1 / scale, a2s = a2 / scale;
        const float cen  = (a1s + a2s) * 0.5f;
        const float half = (a2s - a1s) * 0.5f;
        const float tt = -1.f + (2.f / 13.f) * (float)j;
        const float p  = cen + tt * half;
        const float p0 = floorf(p);
        const float d  = p - p0;
        const float HWf = (float)HW;
        const float m0 = (p0 >= 0.f && p0 < HWf) ? 1.f : 0.f;
        const float m1 = (p0 + 1.f >= 0.f && p0 + 1.f < HWf) ? 1.f : 0.f;
        const int c0i = min(max((int)p0, 0), HW - 1);
        const int c1i = min(max((int)p0 + 1, 0), HW - 1);
        if (isx) { sxw0[j] = (1.f - d) * m0; sxw1[j] = d * m1; sxc0[j] = c0i; sxc1[j] = c1i; }
        else     { syw0[j] = (1.f - d) * m0; syw1[j] = d * m1; syc0[j] = c0i; syc1[j] = c1i; }
    }
    __syncthreads();

    const int g     = t & 31;                   // channel group within half: 32 x 4ch = 128
    const int ph    = t >> 5;                   // 0..7 pixel phase
    const int cbase = ch0 + (g << 2);

    const unsigned short* __restrict__ fb = nullptr;
    const float* __restrict__ fbF = nullptr;
    if (HWC) {
        const unsigned int off = (lvl == 0) ? OFF_P2 : (lvl == 1) ? OFF_P3 : (lvl == 2) ? OFF_P4 : OFF_P5;
        fb = ws + off + cbase;
    } else {
        fbF = (lvl == 0) ? p2 : (lvl == 1) ? p3 : (lvl == 2) ? p4 : p5;
    }
    const int HW2 = HW * HW;

    for (int p = ph; p < PIX; p += 8) {
        const int oy = p / 7;
        const int ox = p - oy * 7;
        float4 m = make_float4(-3.4e38f, -3.4e38f, -3.4e38f, -3.4e38f);
        #pragma unroll
        for (int sy = 0; sy < 2; ++sy) {
            const int i = oy * 2 + sy;
            const float wy0 = syw0[i], wy1 = syw1[i];
            const int   yc0 = syc0[i], yc1 = syc1[i];
            #pragma unroll
            for (int sx = 0; sx < 2; ++sx) {
                const int j = ox * 2 + sx;
                const float wx0 = sxw0[j], wx1 = sxw1[j];
                const int   xc0 = sxc0[j], xc1 = sxc1[j];
                float4 v;
                if (HWC) {
                    const ushort4 a00 = *(const ushort4*)(fb + ((yc0 * HW + xc0) << 8));
                    const ushort4 a01 = *(const ushort4*)(fb + ((yc0 * HW + xc1) << 8));
                    const ushort4 a10 = *(const ushort4*)(fb + ((yc1 * HW + xc0) << 8));
                    const ushort4 a11 = *(const ushort4*)(fb + ((yc1 * HW + xc1) << 8));
                    v.x = wy0 * (wx0 * bf2f(a00.x) + wx1 * bf2f(a01.x)) + wy1 * (wx0 * bf2f(a10.x) + wx1 * bf2f(a11.x));
                    v.y = wy0 * (wx0 * bf2f(a00.y) + wx1 * bf2f(a01.y)) + wy1 * (wx0 * bf2f(a10.y) + wx1 * bf2f(a11.y));
                    v.z = wy0 * (wx0 * bf2f(a00.z) + wx1 * bf2f(a01.z)) + wy1 * (wx0 * bf2f(a10.z) + wx1 * bf2f(a11.z));
                    v.w = wy0 * (wx0 * bf2f(a00.w) + wx1 * bf2f(a01.w)) + wy1 * (wx0 * bf2f(a10.w) + wx1 * bf2f(a11.w));
                } else {
                    float vv[4];
                    #pragma unroll
                    for (int k = 0; k < 4; ++k) {
                        const size_t cb = (size_t)(cbase + k) * HW2;
                        const float a00 = fbF[cb + yc0 * HW + xc0];
                        const float a01 = fbF[cb + yc0 * HW + xc1];
                        const float a10 = fbF[cb + yc1 * HW + xc0];
                        const float a11 = fbF[cb + yc1 * HW + xc1];
                        vv[k] = wy0 * (wx0 * a00 + wx1 * a01) + wy1 * (wx0 * a10 + wx1 * a11);
                    }
                    v.x = vv[0]; v.y = vv[1]; v.z = vv[2]; v.w = vv[3];
                }
                m.x = fmaxf(m.x, v.x);
                m.y = fmaxf(m.y, v.y);
                m.z = fmaxf(m.z, v.z);
                m.w = fmaxf(m.w, v.w);
            }
        }
        *(float4*)&sout[p * SROW + (g << 2)] = m;
    }
    __syncthreads();

    const size_t ob = (size_t)n * OUT_PER_ROI + (size_t)ch0 * PIX;
    for (int o = t; o < HALF_OUT; o += 256) {
        const int c  = o / PIX;
        const int pp = o - c * PIX;
        out[ob + o] = sout[pp * SROW + c];
    }
}

extern "C" void kernel_launch(void* const* d_in, const int* in_sizes, int n_in,
                              void* d_out, int out_size, void* d_ws, size_t ws_size,
                              hipStream_t stream) {
    const float* p2   = (const float*)d_in[0];
    const float* p3   = (const float*)d_in[1];
    const float* p4   = (const float*)d_in[2];
    const float* p5   = (const float*)d_in[3];
    const float* rois = (const float*)d_in[4];
    float* out = (float*)d_out;
    const int N = in_sizes[4] / 5;

    const size_t need = (size_t)WS_ELEMS * sizeof(unsigned short);
    if (ws_size >= need) {
        unsigned short* ws = (unsigned short*)d_ws;
        transpose_all_k<<<1360, 256, 0, stream>>>(p2, p3, p4, p5, ws);
        roi_align_k<true><<<dim3(N, 2), 256, 0, stream>>>(p2, p3, p4, p5, ws, rois, out);
    } else {
        roi_align_k<false><<<dim3(N, 2), 256, 0, stream>>>(p2, p3, p4, p5, nullptr, rois, out);
    }
}

// Round 4
// 56.248 us; speedup vs baseline: 1.5412x; 1.0041x over previous
//
#include <hip/hip_runtime.h>
#include <math.h>

#define C_CH 256
#define PRE 14
#define NPOOL 7
#define PIX (NPOOL * NPOOL)            // 49
#define OUT_PER_ROI (C_CH * PIX)       // 12544
#define HALF_C 128
#define HALF_OUT (HALF_C * PIX)        // 6272
#define SROW 132                       // sout: 128 + 4 pad

// level offsets in bf16 elements inside HWC workspace
#define OFF_P2 0
#define OFF_P3 16777216u
#define OFF_P4 20971520u
#define OFF_P5 22020096u
#define WS_ELEMS 22282240u

#define RB 528                         // transpose LDS row stride in bytes (512 + 16)

static __device__ __forceinline__ unsigned short f2bf(float f) {
    unsigned int u = __float_as_uint(f);
    unsigned int r = (u + 0x7FFFu + ((u >> 16) & 1u)) >> 16;   // RNE
    return (unsigned short)r;
}
static __device__ __forceinline__ float bf2f(unsigned short b) {
    return __uint_as_float(((unsigned int)b) << 16);
}

// ---------------- fused transpose CHW fp32 -> HWC bf16 (all 4 levels) ----------------
// Tile: 128 hw x 256 ch. Phase 1: 512B-contiguous float4 loads per channel plane
// (half-wave = 32 lanes x 16B), in-register 4x4 transpose, swizzled ds_write_b64.
// Phase 2: ds_read_b128 + 1KB-contiguous global stores per wave.
__global__ __launch_bounds__(256) void transpose_all_k(
    const float* __restrict__ p2, const float* __restrict__ p3,
    const float* __restrict__ p4, const float* __restrict__ p5,
    unsigned short* __restrict__ ws) {
    __shared__ unsigned char lds[128 * RB];    // 67584 B

    int b = blockIdx.x;
    const float* __restrict__ src;
    int HW2; unsigned int off;
    if (b < 512)      { src = p2; HW2 = 65536; off = OFF_P2; }
    else if (b < 640) { src = p3; HW2 = 16384; off = OFF_P3; b -= 512; }
    else if (b < 672) { src = p4; HW2 = 4096;  off = OFF_P4; b -= 640; }
    else              { src = p5; HW2 = 1024;  off = OFF_P5; b -= 672; }
    const int hw0 = b << 7;                    // 128 hw per block

    const int t   = threadIdx.x;
    const int hwq = t & 31;                    // hw quad 0..31 (covers 128 hw)
    const int cg  = t >> 5;                    // 0..7

    const int key = (hwq & 7) << 4;            // XOR swizzle key (bits 4..6)

    #pragma unroll
    for (int s = 0; s < 8; ++s) {
        const int c0 = (cg << 2) + (s << 5);   // channel base, 4 planes
        const float* g = src + (size_t)c0 * HW2 + hw0 + (hwq << 2);
        const float4 a0 = *(const float4*)(g);
        const float4 a1 = *(const float4*)(g + HW2);
        const float4 a2 = *(const float4*)(g + 2 * (size_t)HW2);
        const float4 a3 = *(const float4*)(g + 3 * (size_t)HW2);
        const int cb = (c0 << 1) ^ key;        // swizzled column byte
        unsigned char* base = &lds[(hwq << 2) * RB + cb];
        ushort4 w;
        w.x = f2bf(a0.x); w.y = f2bf(a1.x); w.z = f2bf(a2.x); w.w = f2bf(a3.x);
        *(ushort4*)(base) = w;
        w.x = f2bf(a0.y); w.y = f2bf(a1.y); w.z = f2bf(a2.y); w.w = f2bf(a3.y);
        *(ushort4*)(base + RB) = w;
        w.x = f2bf(a0.z); w.y = f2bf(a1.z); w.z = f2bf(a2.z); w.w = f2bf(a3.z);
        *(ushort4*)(base + 2 * RB) = w;
        w.x = f2bf(a0.w); w.y = f2bf(a1.w); w.z = f2bf(a2.w); w.w = f2bf(a3.w);
        *(ushort4*)(base + 3 * RB) = w;
    }
    __syncthreads();

    // Phase 2: each pass covers 8 rows x 512B; wave writes 1KB contiguous.
    char* __restrict__ dstb = (char*)(ws + off + ((size_t)hw0 << 8));
    const int chunk = t & 31;
    const int hwl   = t >> 5;                  // 0..7
    #pragma unroll
    for (int p = 0; p < 16; ++p) {
        const int hw = (p << 3) + hwl;
        const int k2 = ((hw >> 2) & 7) << 4;
        const uint4 v = *(const uint4*)&lds[hw * RB + ((chunk << 4) ^ k2)];
        *(uint4*)(dstb + hw * 512 + (chunk << 4)) = v;
    }
}

// ---------------- main ROI-align + 2x2 maxpool (128 channels per block) ----------------
template <bool HWC>
__global__ __launch_bounds__(256, 6) void roi_align_k(
    const float* __restrict__ p2, const float* __restrict__ p3,
    const float* __restrict__ p4, const float* __restrict__ p5,
    const unsigned short* __restrict__ ws, const float* __restrict__ rois,
    float* __restrict__ out) {

    __shared__ float sxw0[PRE], sxw1[PRE], syw0[PRE], syw1[PRE];
    __shared__ int   sxc0[PRE], sxc1[PRE], syc0[PRE], syc1[PRE];
    __shared__ float sout[PIX * SROW];          // 25872 B

    const int n   = blockIdx.x;
    const int ch0 = blockIdx.y << 7;            // 0 or 128
    const float x1 = rois[n * 5 + 1];
    const float y1 = rois[n * 5 + 2];
    const float x2 = rois[n * 5 + 3];
    const float y2 = rois[n * 5 + 4];

    float w = x2 - x1; w = (w <= 0.f) ? 1e-14f : w;
    float h = y2 - y1; h = (h <= 0.f) ? 1e-14f : h;
    float kf = 4.f + log2f(sqrtf(w * h) * (1.f / 224.f));
    kf = fminf(fmaxf(kf, 2.f), 5.f);
    const float kr = rintf(kf);                 // round-half-even == jnp.round
    const int   lvl = (int)kr - 2;              // 0..3
    const float scale = exp2f(kr);
    const int   HW = 256 >> lvl;

    const int t = threadIdx.x;

    if (t < 2 * PRE) {
        const bool isx = t < PRE;
        const int  j = isx ? t : t - PRE;
        const float a1 = isx ? x1 : y1;
        const float a2 = isx ? x2 : y2;
        const float a1s = a1 / scale, a2s = a2 / scale;
        const float cen  = (a1s + a2s) * 0.5f;
        const float half = (a2s - a1s) * 0.5f;
        const float tt = -1.f + (2.f / 13.f) * (float)j;
        const float p  = cen + tt * half;
        const float p0 = floorf(p);
        const float d  = p - p0;
        const float HWf = (float)HW;
        const float m0 = (p0 >= 0.f && p0 < HWf) ? 1.f : 0.f;
        const float m1 = (p0 + 1.f >= 0.f && p0 + 1.f < HWf) ? 1.f : 0.f;
        const int c0i = min(max((int)p0, 0), HW - 1);
        const int c1i = min(max((int)p0 + 1, 0), HW - 1);
        if (isx) { sxw0[j] = (1.f - d) * m0; sxw1[j] = d * m1; sxc0[j] = c0i; sxc1[j] = c1i; }
        else     { syw0[j] = (1.f - d) * m0; syw1[j] = d * m1; syc0[j] = c0i; syc1[j] = c1i; }
    }
    __syncthreads();

    const int g     = t & 31;                   // channel group within half: 32 x 4ch = 128
    const int ph    = t >> 5;                   // 0..7 pixel phase
    const int cbase = ch0 + (g << 2);

    const unsigned short* __restrict__ fb = nullptr;
    const float* __restrict__ fbF = nullptr;
    if (HWC) {
        const unsigned int off = (lvl == 0) ? OFF_P2 : (lvl == 1) ? OFF_P3 : (lvl == 2) ? OFF_P4 : OFF_P5;
        fb = ws + off + cbase;
    } else {
        fbF = (lvl == 0) ? p2 : (lvl == 1) ? p3 : (lvl == 2) ? p4 : p5;
    }
    const int HW2 = HW * HW;

    for (int p = ph; p < PIX; p += 8) {
        const int oy = p / 7;
        const int ox = p - oy * 7;
        float4 m = make_float4(-3.4e38f, -3.4e38f, -3.4e38f, -3.4e38f);
        #pragma unroll
        for (int sy = 0; sy < 2; ++sy) {
            const int i = oy * 2 + sy;
            const float wy0 = syw0[i], wy1 = syw1[i];
            const int   yc0 = syc0[i], yc1 = syc1[i];
            #pragma unroll
            for (int sx = 0; sx < 2; ++sx) {
                const int j = ox * 2 + sx;
                const float wx0 = sxw0[j], wx1 = sxw1[j];
                const int   xc0 = sxc0[j], xc1 = sxc1[j];
                float4 v;
                if (HWC) {
                    const ushort4 a00 = *(const ushort4*)(fb + ((yc0 * HW + xc0) << 8));
                    const ushort4 a01 = *(const ushort4*)(fb + ((yc0 * HW + xc1) << 8));
                    const ushort4 a10 = *(const ushort4*)(fb + ((yc1 * HW + xc0) << 8));
                    const ushort4 a11 = *(const ushort4*)(fb + ((yc1 * HW + xc1) << 8));
                    v.x = wy0 * (wx0 * bf2f(a00.x) + wx1 * bf2f(a01.x)) + wy1 * (wx0 * bf2f(a10.x) + wx1 * bf2f(a11.x));
                    v.y = wy0 * (wx0 * bf2f(a00.y) + wx1 * bf2f(a01.y)) + wy1 * (wx0 * bf2f(a10.y) + wx1 * bf2f(a11.y));
                    v.z = wy0 * (wx0 * bf2f(a00.z) + wx1 * bf2f(a01.z)) + wy1 * (wx0 * bf2f(a10.z) + wx1 * bf2f(a11.z));
                    v.w = wy0 * (wx0 * bf2f(a00.w) + wx1 * bf2f(a01.w)) + wy1 * (wx0 * bf2f(a10.w) + wx1 * bf2f(a11.w));
                } else {
                    float vv[4];
                    #pragma unroll
                    for (int k = 0; k < 4; ++k) {
                        const size_t cb = (size_t)(cbase + k) * HW2;
                        const float a00 = fbF[cb + yc0 * HW + xc0];
                        const float a01 = fbF[cb + yc0 * HW + xc1];
                        const float a10 = fbF[cb + yc1 * HW + xc0];
                        const float a11 = fbF[cb + yc1 * HW + xc1];
                        vv[k] = wy0 * (wx0 * a00 + wx1 * a01) + wy1 * (wx0 * a10 + wx1 * a11);
                    }
                    v.x = vv[0]; v.y = vv[1]; v.z = vv[2]; v.w = vv[3];
                }
                m.x = fmaxf(m.x, v.x);
                m.y = fmaxf(m.y, v.y);
                m.z = fmaxf(m.z, v.z);
                m.w = fmaxf(m.w, v.w);
            }
        }
        *(float4*)&sout[p * SROW + (g << 2)] = m;
    }
    __syncthreads();

    const size_t ob = (size_t)n * OUT_PER_ROI + (size_t)ch0 * PIX;
    for (int o = t; o < HALF_OUT; o += 256) {
        const int c  = o / PIX;
        const int pp = o - c * PIX;
        out[ob + o] = sout[pp * SROW + c];
    }
}

extern "C" void kernel_launch(void* const* d_in, const int* in_sizes, int n_in,
                              void* d_out, int out_size, void* d_ws, size_t ws_size,
                              hipStream_t stream) {
    const float* p2   = (const float*)d_in[0];
    const float* p3   = (const float*)d_in[1];
    const float* p4   = (const float*)d_in[2];
    const float* p5   = (const float*)d_in[3];
    const float* rois = (const float*)d_in[4];
    float* out = (float*)d_out;
    const int N = in_sizes[4] / 5;

    const size_t need = (size_t)WS_ELEMS * sizeof(unsigned short);
    if (ws_size >= need) {
        unsigned short* ws = (unsigned short*)d_ws;
        transpose_all_k<<<680, 256, 0, stream>>>(p2, p3, p4, p5, ws);
        roi_align_k<true><<<dim3(N, 2), 256, 0, stream>>>(p2, p3, p4, p5, ws, rois, out);
    } else {
        roi_align_k<false><<<dim3(N, 2), 256, 0, stream>>>(p2, p3, p4, p5, nullptr, rois, out);
    }
}